// Round 12
// baseline (405.377 us; speedup 1.0000x reference)
//
#include <hip/hip_runtime.h>
#include <hip/hip_bf16.h>

typedef __bf16 bf16x8 __attribute__((ext_vector_type(8)));
typedef float  f32x16 __attribute__((ext_vector_type(16)));

// ---------- helpers ----------
static __device__ __forceinline__ unsigned short f2bf(float f) {
  unsigned int u = __float_as_uint(f);
  u += 0x7FFFu + ((u >> 16) & 1u);   // round-to-nearest-even
  return (unsigned short)(u >> 16);
}

static __device__ __forceinline__ void gl_lds16(const void* g, void* l) {
  __builtin_amdgcn_global_load_lds(
      (const __attribute__((address_space(1))) void*)g,
      (__attribute__((address_space(3))) void*)l,
      16, 0, 0);
}

// ---------- cast x: f32 -> bf16 ----------
__global__ __launch_bounds__(256) void cast_f32_bf16(
    const float* __restrict__ in, unsigned short* __restrict__ out, int n) {
  int i = (blockIdx.x * 256 + threadIdx.x) * 4;
  const int stride = gridDim.x * 256 * 4;
  for (; i < n; i += stride) {
    float4 f = *(const float4*)(in + i);
    ushort4 o;
    o.x = f2bf(f.x); o.y = f2bf(f.y); o.z = f2bf(f.z); o.w = f2bf(f.w);
    *(ushort4*)(out + i) = o;
  }
}

// ---------- transpose-cast Wq|Wk|Wv in one launch (z picks the matrix) ----------
__global__ __launch_bounds__(256) void transpose_cast_w3(
    const float* __restrict__ w0, const float* __restrict__ w1,
    const float* __restrict__ w2, unsigned short* __restrict__ wt) {
  __shared__ float tile[16][17];
  const float* w = blockIdx.z == 0 ? w0 : (blockIdx.z == 1 ? w1 : w2);
  unsigned short* o = wt + (size_t)blockIdx.z * 1048576;
  const int tx = threadIdx.x & 15, ty = threadIdx.x >> 4;
  const int bx = blockIdx.x * 16, by = blockIdx.y * 16;
  tile[ty][tx] = w[(size_t)(by + ty) * 1024 + bx + tx];
  __syncthreads();
  o[(size_t)(bx + ty) * 1024 + by + tx] = f2bf(tile[tx][ty]);
}

// ---------- 128x128-tile bf16 GEMM, BK=64, r7 schedule, MFMA 32x32x16 ----------
// B given transposed ([N][K]). XCD-locality remap: d2 -> (ty=d2%gy, tx=d2/gy).
// LDS 32 KiB: A 16K as [kk 0..1][row 0..127][32e=64B], B same -- but the four
// 16B slots of each row are stored XOR-permuted: stored[p] = orig[p ^ (row&3)]
// (pre-swizzled GLOBAL source, linear LDS dest -> gl_lds16-compatible, rule 21;
// source permutation stays inside the row's 64B line -> coalescing unchanged).
// 32x32 fragment read (32 rows x 32B, pitch 64B) would hit half the banks
// (16/bank); the slot-XOR spreads each row-residue class onto a disjoint
// 8-bank group -> exactly 8 dwords/bank = conflict-free floor.
// MFMA 32x32x16 (m119: 2495 vs 2176 TF ceiling, half the instructions).
// Fragment layouts: A row=l&31,k=(l>>5)*8+j (analog of verified 16x16);
// C/D col=lane&31, row=(reg&3)+8*(reg>>2)+4*(lane>>5) [verified m74/m101].
// MODE 3: fused-QKV split write (Cv = qb base; kb = +16Mi elems, vt = +32Mi)
// MODE 4: scores + fused exp + per-block partial row-sums
// MODE 5: PV; inv computed IN-BLOCK from the 16 partials
template <int MODE>
__global__ __launch_bounds__(256, 2) void gemm_bt(
    const unsigned short* __restrict__ A, int lda, size_t astride,
    const unsigned short* __restrict__ B, int ldb, size_t bstride,
    int K, void* __restrict__ Cv, int ldc, size_t cstride,
    float* __restrict__ aux) {
  __shared__ __align__(16) unsigned char lds[32768];  // A 16K | B 16K
  __shared__ float smInv[128];
  const unsigned d2 = blockIdx.x + gridDim.x * blockIdx.y;
  const unsigned ty = d2 % gridDim.y;
  const unsigned tx = d2 / gridDim.y;
  const int bn0 = tx * 128;
  const int bm0 = ty * 128;
  A += (size_t)blockIdx.z * astride;
  B += (size_t)blockIdx.z * bstride;

  const int tid = threadIdx.x;
  const int wid = tid >> 6, lane = tid & 63;
  const int wr = wid >> 1, wc = wid & 1;
  const int l31 = lane & 31, hi = lane >> 5;

  if constexpr (MODE == 5) {  // inv[row] for this block's 128 rows
    if (tid < 128) {
      const float* p = aux + (size_t)blockIdx.z * 32768 + bm0 + tid;
      float s = 0.f;
#pragma unroll
      for (int j = 0; j < 16; ++j) s += p[j * 2048];
      smInv[tid] = 1.0f / s;   // visible after iter-0 __syncthreads
    }
  }

  // staging: chunk c = j*256 + tid -> kk = j>>1, row = (j&1)*64 + tid>>2;
  // 16B slot pre-swizzled: source slot = (tid&3) ^ (destrow&3), destrow&3 = (tid>>2)&3
  const int sr = tid >> 2;
  const int ssub = ((tid & 3) ^ (sr & 3)) * 8;
  size_t aoff[4], boff[4];
#pragma unroll
  for (int j = 0; j < 4; ++j) {
    const int r = (j & 1) * 64 + sr;
    const int kko = (j >> 1) * 32;
    aoff[j] = (size_t)(bm0 + r) * lda + kko + ssub;
    boff[j] = (size_t)(bn0 + r) * ldb + kko + ssub;
  }
  unsigned char* dstA = lds + wid * 1024;           // + j*4096
  unsigned char* dstB = lds + 16384 + wid * 1024;   // + j*4096

  f32x16 acc[2][2] = {};
  const int nkt = K >> 6;
  for (int kt = 0; kt < nkt; ++kt) {
    const int kc = kt << 6;
#pragma unroll
    for (int j = 0; j < 4; ++j) {
      gl_lds16(A + aoff[j] + kc, dstA + j * 4096);
      gl_lds16(B + boff[j] + kc, dstB + j * 4096);
    }
    __syncthreads();

#pragma unroll
    for (int ks = 0; ks < 4; ++ks) {            // 4 x K=16 steps
      const int kk = ks >> 1;
      const int slot = (((ks & 1) << 1) | hi) ^ (l31 & 3);   // read-side XOR
      bf16x8 af[2], bg[2];
#pragma unroll
      for (int cm = 0; cm < 2; ++cm)
        af[cm] = *(const bf16x8*)(lds + kk * 8192 + (wr * 64 + cm * 32 + l31) * 64 + slot * 16);
#pragma unroll
      for (int cn = 0; cn < 2; ++cn)
        bg[cn] = *(const bf16x8*)(lds + 16384 + kk * 8192 + (wc * 64 + cn * 32 + l31) * 64 + slot * 16);
#pragma unroll
      for (int cm = 0; cm < 2; ++cm)
#pragma unroll
        for (int cn = 0; cn < 2; ++cn)
          acc[cm][cn] = __builtin_amdgcn_mfma_f32_32x32x16_bf16(af[cm], bg[cn], acc[cm][cn], 0, 0, 0);
    }
    __syncthreads();
  }

  // epilogue: C/D layout col = lane&31, row = (reg&3)+8*(reg>>2)+4*hi  [m74/m101]
  if constexpr (MODE == 3) {
#pragma unroll
    for (int cm = 0; cm < 2; ++cm)
#pragma unroll
      for (int cn = 0; cn < 2; ++cn)
#pragma unroll
        for (int g = 0; g < 16; ++g) {
          const int row = bm0 + wr * 64 + cm * 32 + (g & 3) + 8 * (g >> 2) + 4 * hi;
          const int col = bn0 + wc * 64 + cn * 32 + l31;
          const float v = acc[cm][cn][g];
          unsigned short* q = (unsigned short*)Cv;
          if (col < 1024) {
            q[(size_t)row * 1024 + col] = f2bf(v);
          } else if (col < 2048) {
            q[16777216u + (size_t)row * 1024 + (col - 1024)] = f2bf(v);
          } else {
            const int b = row >> 11, s = row & 2047;
            q[33554432u + ((size_t)(b * 1024 + (col - 2048))) * 2048 + s] = f2bf(v);
          }
        }
  } else if constexpr (MODE == 4) {
    __shared__ float redsm[128][2];
    unsigned short* pp = (unsigned short*)Cv + (size_t)blockIdx.z * cstride;
    float rs[2][16];
#pragma unroll
    for (int cm = 0; cm < 2; ++cm)
#pragma unroll
      for (int g = 0; g < 16; ++g) rs[cm][g] = 0.f;
#pragma unroll
    for (int cm = 0; cm < 2; ++cm)
#pragma unroll
      for (int cn = 0; cn < 2; ++cn)
#pragma unroll
        for (int g = 0; g < 16; ++g) {
          const float e = exp2f(acc[cm][cn][g] * 0.045084220027780106f);  // exp(acc/32)
          rs[cm][g] += e;
          const int row = bm0 + wr * 64 + cm * 32 + (g & 3) + 8 * (g >> 2) + 4 * hi;
          const int col = bn0 + wc * 64 + cn * 32 + l31;
          pp[(size_t)row * ldc + col] = f2bf(e);
        }
    // reduce each row's partial over the 32 col-lanes (bit5 = hi untouched)
#pragma unroll
    for (int cm = 0; cm < 2; ++cm)
#pragma unroll
      for (int g = 0; g < 16; ++g) {
        float s = rs[cm][g];
        s += __shfl_xor(s, 1); s += __shfl_xor(s, 2);
        s += __shfl_xor(s, 4); s += __shfl_xor(s, 8);
        s += __shfl_xor(s, 16);
        rs[cm][g] = s;
      }
    if (l31 == 0) {
#pragma unroll
      for (int cm = 0; cm < 2; ++cm)
#pragma unroll
        for (int g = 0; g < 16; ++g)
          redsm[wr * 64 + cm * 32 + (g & 3) + 8 * (g >> 2) + 4 * hi][wc] = rs[cm][g];
    }
    __syncthreads();
    if (tid < 128)
      aux[((size_t)blockIdx.z * 16 + tx) * 2048 + bm0 + tid] =
          redsm[tid][0] + redsm[tid][1];
  } else {  // MODE 5
    float* op = (float*)Cv + (size_t)blockIdx.z * cstride;
#pragma unroll
    for (int cm = 0; cm < 2; ++cm)
#pragma unroll
      for (int g = 0; g < 16; ++g) {
        const int row = bm0 + wr * 64 + cm * 32 + (g & 3) + 8 * (g >> 2) + 4 * hi;
        const float iv = smInv[wr * 64 + cm * 32 + (g & 3) + 8 * (g >> 2) + 4 * hi];
#pragma unroll
        for (int cn = 0; cn < 2; ++cn) {
          const int col = bn0 + wc * 64 + cn * 32 + l31;
          op[(size_t)row * ldc + col] = acc[cm][cn][g] * iv;
        }
      }
  }
}

// ---------- launch ----------
extern "C" void kernel_launch(void* const* d_in, const int* in_sizes, int n_in,
                              void* d_out, int out_size, void* d_ws, size_t ws_size,
                              hipStream_t stream) {
  const float* x  = (const float*)d_in[0];
  const float* Wq = (const float*)d_in[1];
  const float* Wk = (const float*)d_in[2];
  const float* Wv = (const float*)d_in[3];
  float* out = (float*)d_out;
  char* ws = (char*)d_ws;

  // workspace layout (bytes)
  unsigned short* xb     = (unsigned short*)ws;                  // 33.5 MB (dead after QKV)
  unsigned short* wt_all = (unsigned short*)(ws + 33554432);     // 6 MB: WqT|WkT|WvT [3072][1024]
  unsigned short* qb     = (unsigned short*)(ws + 39845888);     // 33.5 MB
  unsigned short* kb     = qb + 16777216;                        // 33.5 MB
  unsigned short* vt     = kb + 16777216;                        // 33.5 MB (vT: [b*1024+e][s])
  const size_t off_scores = 140509184ull;                        // end of vt

  // per-batch attention scratch: P' bf16 8 MiB + partials 128 KiB
  const size_t per_b = 8388608ull + 131072ull;
  int G; char *pPc, *partc;
  const size_t avail = ws_size > off_scores ? ws_size - off_scores : 0;
  G = (int)(avail / per_b); if (G > 8) G = 8;
  if (G >= 1) {
    pPc   = ws + off_scores;
    partc = pPc + (size_t)G * 8388608ull;
  } else {
    G = 2;  // fallback: reuse xb region (33.5 MB >= 2 x 8.53 MB); xb dead after QKV
    pPc   = ws;
    partc = ws + 2 * 8388608ull;
  }

  cast_f32_bf16<<<2048, 256, 0, stream>>>(x, xb, 16384 * 1024);
  transpose_cast_w3<<<dim3(64, 64, 3), 256, 0, stream>>>(Wq, Wk, Wv, wt_all);

  // fused QKV projection: M=16384, N=3072, K=1024 -- 128^2 tile (r7 structure)
  gemm_bt<3><<<dim3(24, 128), 256, 0, stream>>>(xb, 1024, 0, wt_all, 1024, 0,
                                                1024, qb, 0, 0, nullptr);

  for (int b0 = 0; b0 < 8; b0 += G) {
    const int g = (8 - b0) < G ? (8 - b0) : G;
    const size_t so = (size_t)b0 * 2097152;  // q/k/v/out batch offset (elems)
    // P' = exp(q.k^T/32) bf16 + partial row sums: M=N=2048, K=1024
    gemm_bt<4><<<dim3(16, 16, g), 256, 0, stream>>>(
        qb + so, 1024, 2097152, kb + so, 1024, 2097152, 1024,
        (unsigned short*)pPc, 2048, 4194304, (float*)partc);
    // out = (P'.v) * inv : A=P' [2048][2048] bf16, B^T = vT_b [1024][2048], K=2048
    // (inv computed in-block from the 16 partials; combine kernel folded away)
    gemm_bt<5><<<dim3(8, 16, g), 256, 0, stream>>>(
        (const unsigned short*)pPc, 2048, 4194304,
        vt + so, 2048, 2097152, 2048,
        out + so, 1024, 2097152, (float*)partc);
  }
}

// Round 13
// 361.565 us; speedup vs baseline: 1.1212x; 1.1212x over previous
//
#include <hip/hip_runtime.h>
#include <hip/hip_bf16.h>

typedef __bf16 bf16x8 __attribute__((ext_vector_type(8)));
typedef float  f32x4  __attribute__((ext_vector_type(4)));

// ---------- helpers ----------
static __device__ __forceinline__ unsigned short f2bf(float f) {
  unsigned int u = __float_as_uint(f);
  u += 0x7FFFu + ((u >> 16) & 1u);   // round-to-nearest-even
  return (unsigned short)(u >> 16);
}

static __device__ __forceinline__ void gl_lds16(const void* g, void* l) {
  __builtin_amdgcn_global_load_lds(
      (const __attribute__((address_space(1))) void*)g,
      (__attribute__((address_space(3))) void*)l,
      16, 0, 0);
}

// ---------- cast x: f32 -> bf16 ----------
__global__ __launch_bounds__(256) void cast_f32_bf16(
    const float* __restrict__ in, unsigned short* __restrict__ out, int n) {
  int i = (blockIdx.x * 256 + threadIdx.x) * 4;
  const int stride = gridDim.x * 256 * 4;
  for (; i < n; i += stride) {
    float4 f = *(const float4*)(in + i);
    ushort4 o;
    o.x = f2bf(f.x); o.y = f2bf(f.y); o.z = f2bf(f.z); o.w = f2bf(f.w);
    *(ushort4*)(out + i) = o;
  }
}

// ---------- transpose-cast Wq|Wk|Wv in one launch (z picks the matrix) ----------
__global__ __launch_bounds__(256) void transpose_cast_w3(
    const float* __restrict__ w0, const float* __restrict__ w1,
    const float* __restrict__ w2, unsigned short* __restrict__ wt) {
  __shared__ float tile[16][17];
  const float* w = blockIdx.z == 0 ? w0 : (blockIdx.z == 1 ? w1 : w2);
  unsigned short* o = wt + (size_t)blockIdx.z * 1048576;
  const int tx = threadIdx.x & 15, ty = threadIdx.x >> 4;
  const int bx = blockIdx.x * 16, by = blockIdx.y * 16;
  tile[ty][tx] = w[(size_t)(by + ty) * 1024 + bx + tx];
  __syncthreads();
  o[(size_t)(bx + ty) * 1024 + by + tx] = f2bf(tile[tx][ty]);
}

// ---------- 128x128-tile bf16 GEMM, BK=32 DOUBLE-buffer (32 KB), 16x16x32 ----------
// B given transposed ([N][K]). XCD-locality remap: d2 -> (ty=d2%gy, tx=d2/gy);
// gy%8==0 keeps A-row-panel sharers on one XCD. blockIdx.z batches.
// The untested schedule cell: r8's issue-early/wait-late dbuf (per-wave
// MfmaUtil/Occ = 1.12, best measured) at r7's 32 KB footprint (occ 39%) and
// r2's depth-1 prefetch (no r9 L2 thrash). LDS = 2 buffers x (A 8K | B 8K),
// rows [r][32e=64B]; staging = 16 consecutive rows x 64 B contiguous per
// wave-load; fragment ds_read_b128 row-stride 64 B (conflict-floor).
// Per iter t: STAGE(t+1 -> buf^1) ; 8x asm ds_read(buf t&1) ; lgkmcnt(0)+
// sched_barrier (rule 18) ; setprio(1) 16 MFMA setprio(0) ; vmcnt(0) [stage
// waited AFTER ~300cy of reads+MFMA] ; s_barrier.
// WAR: buf-t reads retire at lgkmcnt(0) before each wave's barrier arrival;
// the overwrite of buf t&1 (STAGE(t+2)) is issued only after that barrier.
// asm ds_reads carry no mem clobber so the compiler cannot alias them vs the
// staging writes and re-insert vmcnt drains (r3/r4 failure mode).
// Scorecard (QKV): r2 175 / r7 164 / r8-dbuf64K 183 / r9-tbuf48K 175 /
// r10-256sq 240 / r12-32x32 188.
// MODE 3: fused-QKV split write (Cv = qb base; kb = +16Mi elems, vt = +32Mi)
// MODE 4: scores + fused exp + per-block partial row-sums
// MODE 5: PV; inv computed IN-BLOCK from the 16 partials
template <int MODE>
__global__ __launch_bounds__(256, 2) void gemm_bt(
    const unsigned short* __restrict__ A, int lda, size_t astride,
    const unsigned short* __restrict__ B, int ldb, size_t bstride,
    int K, void* __restrict__ Cv, int ldc, size_t cstride,
    float* __restrict__ aux) {
  __shared__ __align__(16) unsigned char lds[32768];  // 2 x (A 8K | B 8K)
  __shared__ float smInv[128];
  const unsigned d2 = blockIdx.x + gridDim.x * blockIdx.y;
  const unsigned ty = d2 % gridDim.y;
  const unsigned tx = d2 / gridDim.y;
  const int bn0 = tx * 128;
  const int bm0 = ty * 128;
  A += (size_t)blockIdx.z * astride;
  B += (size_t)blockIdx.z * bstride;

  const int tid = threadIdx.x;
  const int wid = tid >> 6, lane = tid & 63;
  const int wr = wid >> 1, wc = wid & 1;
  const int l15 = lane & 15, kq = lane >> 4;

  if constexpr (MODE == 5) {  // inv[row] for this block's 128 rows
    if (tid < 128) {
      const float* p = aux + (size_t)blockIdx.z * 32768 + bm0 + tid;
      float s = 0.f;
#pragma unroll
      for (int j = 0; j < 16; ++j) s += p[j * 2048];
      smInv[tid] = 1.0f / s;   // consumed in epilogue, long after many barriers
    }
  }

  // staging (r2-proven): element e = wid*512 + lane*8 -> (row e>>5, col e&31);
  // chunks at rows r0 and r0+64. 64 B contiguous per 4 lanes (full cache lines).
  const int e0 = wid * 512 + lane * 8;
  const int r0 = e0 >> 5, c0 = e0 & 31;
  const size_t aoff0 = (size_t)(bm0 + r0) * lda + c0;
  const size_t aoff1 = (size_t)(bm0 + r0 + 64) * lda + c0;
  const size_t boff0 = (size_t)(bn0 + r0) * ldb + c0;
  const size_t boff1 = (size_t)(bn0 + r0 + 64) * ldb + c0;

#define STAGE(t) do { \
    unsigned char* s_ = lds + ((t) & 1) * 16384 + wid * 1024; \
    const int kc_ = (t) << 5; \
    gl_lds16(A + aoff0 + kc_, s_); \
    gl_lds16(A + aoff1 + kc_, s_ + 4096); \
    gl_lds16(B + boff0 + kc_, s_ + 8192); \
    gl_lds16(B + boff1 + kc_, s_ + 12288); \
  } while (0)
#define DSR(dst, addr) asm volatile("ds_read_b128 %0, %1" : "=v"(dst) : "v"(addr))

  // LDS byte-address bases for asm ds_read_b128 ([row][64 B] rows)
  const unsigned ldsbase =
      (unsigned)(unsigned long long)(__attribute__((address_space(3))) unsigned char*)lds;
  const unsigned aA = ldsbase + (wr * 64 + l15) * 64 + kq * 16;          // + buf + mi*1024
  const unsigned aB = ldsbase + 8192 + (wc * 64 + l15) * 64 + kq * 16;   // + buf + ni*1024

  f32x4 acc[4][4] = {};
  const int nkt = K >> 5;

  STAGE(0);
  asm volatile("s_waitcnt vmcnt(0)" ::: "memory");
  __builtin_amdgcn_s_barrier();

  for (int t = 0; t < nkt; ++t) {
    if (t + 1 < nkt) STAGE(t + 1);          // issue early into the other buffer
    const unsigned bofs = (unsigned)(t & 1) * 16384u;

    bf16x8 af[4], bg[4];
#pragma unroll
    for (int mi = 0; mi < 4; ++mi) DSR(af[mi], bofs + aA + mi * 1024);
#pragma unroll
    for (int ni = 0; ni < 4; ++ni) DSR(bg[ni], bofs + aB + ni * 1024);
    asm volatile("s_waitcnt lgkmcnt(0)" ::: "memory");
    __builtin_amdgcn_sched_barrier(0);
    __builtin_amdgcn_s_setprio(1);
#pragma unroll
    for (int mi = 0; mi < 4; ++mi)
#pragma unroll
      for (int ni = 0; ni < 4; ++ni)
        acc[mi][ni] = __builtin_amdgcn_mfma_f32_16x16x32_bf16(af[mi], bg[ni], acc[mi][ni], 0, 0, 0);
    __builtin_amdgcn_s_setprio(0);
    asm volatile("s_waitcnt vmcnt(0)" ::: "memory");   // wait late (hidden by reads+MFMA)
    __builtin_amdgcn_s_barrier();
  }
#undef STAGE
#undef DSR

  // epilogue: C/D layout col = lane&15, row = (lane>>4)*4 + reg  [verified m89/m91]
  if constexpr (MODE == 3) {
#pragma unroll
    for (int mi = 0; mi < 4; ++mi)
#pragma unroll
      for (int ni = 0; ni < 4; ++ni)
#pragma unroll
        for (int r = 0; r < 4; ++r) {
          const int row = bm0 + wr * 64 + mi * 16 + kq * 4 + r;
          const int col = bn0 + wc * 64 + ni * 16 + l15;
          const float v = acc[mi][ni][r];
          unsigned short* q = (unsigned short*)Cv;
          if (col < 1024) {
            q[(size_t)row * 1024 + col] = f2bf(v);
          } else if (col < 2048) {
            q[16777216u + (size_t)row * 1024 + (col - 1024)] = f2bf(v);
          } else {
            const int b = row >> 11, s = row & 2047;
            q[33554432u + ((size_t)(b * 1024 + (col - 2048))) * 2048 + s] = f2bf(v);
          }
        }
  } else if constexpr (MODE == 4) {
    __shared__ float redsm[128][2];
    unsigned short* pp = (unsigned short*)Cv + (size_t)blockIdx.z * cstride;
    float rs[4][4];
#pragma unroll
    for (int mi = 0; mi < 4; ++mi)
#pragma unroll
      for (int r = 0; r < 4; ++r) rs[mi][r] = 0.f;
#pragma unroll
    for (int mi = 0; mi < 4; ++mi)
#pragma unroll
      for (int ni = 0; ni < 4; ++ni)
#pragma unroll
        for (int r = 0; r < 4; ++r) {
          const float e = exp2f(acc[mi][ni][r] * 0.045084220027780106f);  // exp(acc/32)
          rs[mi][r] += e;
          const int row = bm0 + wr * 64 + mi * 16 + kq * 4 + r;
          const int col = bn0 + wc * 64 + ni * 16 + l15;
          pp[(size_t)row * ldc + col] = f2bf(e);
        }
#pragma unroll
    for (int mi = 0; mi < 4; ++mi)
#pragma unroll
      for (int r = 0; r < 4; ++r) {
        float s = rs[mi][r];
        s += __shfl_xor(s, 1); s += __shfl_xor(s, 2);
        s += __shfl_xor(s, 4); s += __shfl_xor(s, 8);
        rs[mi][r] = s;
      }
    if (l15 == 0) {
#pragma unroll
      for (int mi = 0; mi < 4; ++mi)
#pragma unroll
        for (int r = 0; r < 4; ++r)
          redsm[wr * 64 + mi * 16 + kq * 4 + r][wc] = rs[mi][r];
    }
    __syncthreads();
    if (tid < 128)
      aux[((size_t)blockIdx.z * 16 + tx) * 2048 + bm0 + tid] =
          redsm[tid][0] + redsm[tid][1];
  } else {  // MODE 5
    float* op = (float*)Cv + (size_t)blockIdx.z * cstride;
#pragma unroll
    for (int mi = 0; mi < 4; ++mi)
#pragma unroll
      for (int r = 0; r < 4; ++r) {
        const int row = bm0 + wr * 64 + mi * 16 + kq * 4 + r;
        const float iv = smInv[wr * 64 + mi * 16 + kq * 4 + r];
#pragma unroll
        for (int ni = 0; ni < 4; ++ni) {
          const int col = bn0 + wc * 64 + ni * 16 + l15;
          op[(size_t)row * ldc + col] = acc[mi][ni][r] * iv;
        }
      }
  }
}

// ---------- launch ----------
extern "C" void kernel_launch(void* const* d_in, const int* in_sizes, int n_in,
                              void* d_out, int out_size, void* d_ws, size_t ws_size,
                              hipStream_t stream) {
  const float* x  = (const float*)d_in[0];
  const float* Wq = (const float*)d_in[1];
  const float* Wk = (const float*)d_in[2];
  const float* Wv = (const float*)d_in[3];
  float* out = (float*)d_out;
  char* ws = (char*)d_ws;

  // workspace layout (bytes)
  unsigned short* xb     = (unsigned short*)ws;                  // 33.5 MB (dead after QKV)
  unsigned short* wt_all = (unsigned short*)(ws + 33554432);     // 6 MB: WqT|WkT|WvT [3072][1024]
  unsigned short* qb     = (unsigned short*)(ws + 39845888);     // 33.5 MB
  unsigned short* kb     = qb + 16777216;                        // 33.5 MB
  unsigned short* vt     = kb + 16777216;                        // 33.5 MB (vT: [b*1024+e][s])
  const size_t off_scores = 140509184ull;                        // end of vt

  // per-batch attention scratch: P' bf16 8 MiB + partials 128 KiB
  const size_t per_b = 8388608ull + 131072ull;
  int G; char *pPc, *partc;
  const size_t avail = ws_size > off_scores ? ws_size - off_scores : 0;
  G = (int)(avail / per_b); if (G > 8) G = 8;
  if (G >= 1) {
    pPc   = ws + off_scores;
    partc = pPc + (size_t)G * 8388608ull;
  } else {
    G = 2;  // fallback: reuse xb region (33.5 MB >= 2 x 8.53 MB); xb dead after QKV
    pPc   = ws;
    partc = ws + 2 * 8388608ull;
  }

  cast_f32_bf16<<<2048, 256, 0, stream>>>(x, xb, 16384 * 1024);
  transpose_cast_w3<<<dim3(64, 64, 3), 256, 0, stream>>>(Wq, Wk, Wv, wt_all);

  // fused QKV projection: M=16384, N=3072, K=1024 -- 128^2 tile
  gemm_bt<3><<<dim3(24, 128), 256, 0, stream>>>(xb, 1024, 0, wt_all, 1024, 0,
                                                1024, qb, 0, 0, nullptr);

  for (int b0 = 0; b0 < 8; b0 += G) {
    const int g = (8 - b0) < G ? (8 - b0) : G;
    const size_t so = (size_t)b0 * 2097152;  // q/k/v/out batch offset (elems)
    // P' = exp(q.k^T/32) bf16 + partial row sums: M=N=2048, K=1024
    gemm_bt<4><<<dim3(16, 16, g), 256, 0, stream>>>(
        qb + so, 1024, 2097152, kb + so, 1024, 2097152, 1024,
        (unsigned short*)pPc, 2048, 4194304, (float*)partc);
    // out = (P'.v) * inv : A=P' [2048][2048] bf16, B^T = vT_b [1024][2048], K=2048
    // (inv computed in-block from the 16 partials; combine kernel folded away)
    gemm_bt<5><<<dim3(8, 16, g), 256, 0, stream>>>(
        (const unsigned short*)pPc, 2048, 4194304,
        vt + so, 2048, 2097152, 2048,
        out + so, 1024, 2097152, (float*)partc);
  }
}

// Round 14
// 340.899 us; speedup vs baseline: 1.1891x; 1.0606x over previous
//
#include <hip/hip_runtime.h>
#include <hip/hip_bf16.h>

typedef __bf16 bf16x8 __attribute__((ext_vector_type(8)));
typedef float  f32x4  __attribute__((ext_vector_type(4)));

// ---------- helpers ----------
static __device__ __forceinline__ unsigned short f2bf(float f) {
  unsigned int u = __float_as_uint(f);
  u += 0x7FFFu + ((u >> 16) & 1u);   // round-to-nearest-even
  return (unsigned short)(u >> 16);
}

static __device__ __forceinline__ void gl_lds16(const void* g, void* l) {
  __builtin_amdgcn_global_load_lds(
      (const __attribute__((address_space(1))) void*)g,
      (__attribute__((address_space(3))) void*)l,
      16, 0, 0);
}

// ---------- cast x: f32 -> bf16 ----------
__global__ __launch_bounds__(256) void cast_f32_bf16(
    const float* __restrict__ in, unsigned short* __restrict__ out, int n) {
  int i = (blockIdx.x * 256 + threadIdx.x) * 4;
  const int stride = gridDim.x * 256 * 4;
  for (; i < n; i += stride) {
    float4 f = *(const float4*)(in + i);
    ushort4 o;
    o.x = f2bf(f.x); o.y = f2bf(f.y); o.z = f2bf(f.z); o.w = f2bf(f.w);
    *(ushort4*)(out + i) = o;
  }
}

// ---------- transpose-cast Wq|Wk|Wv in one launch (z picks the matrix) ----------
__global__ __launch_bounds__(256) void transpose_cast_w3(
    const float* __restrict__ w0, const float* __restrict__ w1,
    const float* __restrict__ w2, unsigned short* __restrict__ wt) {
  __shared__ float tile[16][17];
  const float* w = blockIdx.z == 0 ? w0 : (blockIdx.z == 1 ? w1 : w2);
  unsigned short* o = wt + (size_t)blockIdx.z * 1048576;
  const int tx = threadIdx.x & 15, ty = threadIdx.x >> 4;
  const int bx = blockIdx.x * 16, by = blockIdx.y * 16;
  tile[ty][tx] = w[(size_t)(by + ty) * 1024 + bx + tx];
  __syncthreads();
  o[(size_t)(bx + ty) * 1024 + by + tx] = f2bf(tile[tx][ty]);
}

// ---------- 128x128-tile bf16 MFMA GEMM, BK=64 single buffer (measured best) ----------
// B given transposed ([N][K]). XCD-locality remap: d2 -> (ty=d2%gy, tx=d2/gy);
// gy%8==0 keeps A-row-panel sharers on one XCD. blockIdx.z batches.
// LDS 32 KiB: A 16K as [kk 0..1][row 0..127][32e=64B], B same. Staging = 16
// consecutive rows x 64 B contiguous per wave-load (full cache lines); LDS
// dest linear; fragment ds_read_b128 row-stride 64 B (conflict-floor).
// Schedule matrix fully bracketed (QKV dispatch): r2-simple 175 / THIS 164 /
// dbuf64K 183 / tbuf48K 175 / 256sq-32K 240 / 32x32-swz 188 / dbuf32K 177 /
// phase-split ports 253-263. Single-buffer BK=64 + ~3 blocks/CU cross-block
// overlap (m114) is the optimum of this structure family; past it requires
// the full co-designed 8-phase 256^2 template (unreproduced, m232 OPEN).
// MODE 3: fused-QKV split write (Cv = qb base; kb = +16Mi elems, vt = +32Mi)
// MODE 4: scores + fused exp + per-block partial row-sums
// MODE 5: PV; inv computed IN-BLOCK from the 16 partials
template <int MODE>
__global__ __launch_bounds__(256, 2) void gemm_bt(
    const unsigned short* __restrict__ A, int lda, size_t astride,
    const unsigned short* __restrict__ B, int ldb, size_t bstride,
    int K, void* __restrict__ Cv, int ldc, size_t cstride,
    float* __restrict__ aux) {
  __shared__ __align__(16) unsigned char lds[32768];  // A 16K | B 16K
  __shared__ float smInv[128];
  const unsigned d2 = blockIdx.x + gridDim.x * blockIdx.y;
  const unsigned ty = d2 % gridDim.y;
  const unsigned tx = d2 / gridDim.y;
  const int bn0 = tx * 128;
  const int bm0 = ty * 128;
  A += (size_t)blockIdx.z * astride;
  B += (size_t)blockIdx.z * bstride;

  const int tid = threadIdx.x;
  const int wid = tid >> 6, lane = tid & 63;
  const int wr = wid >> 1, wc = wid & 1;
  const int l15 = lane & 15, kq = lane >> 4;

  if constexpr (MODE == 5) {  // inv[row] for this block's 128 rows
    if (tid < 128) {
      const float* p = aux + (size_t)blockIdx.z * 32768 + bm0 + tid;
      float s = 0.f;
#pragma unroll
      for (int j = 0; j < 16; ++j) s += p[j * 2048];
      smInv[tid] = 1.0f / s;   // visible after iter-0 __syncthreads
    }
  }

  // staging: chunk c = j*256 + tid -> kk = j>>1, row = (j&1)*64 + tid>>2, sub = tid&3
  const int sr = tid >> 2;
  const int ssub = (tid & 3) * 8;
  size_t aoff[4], boff[4];
#pragma unroll
  for (int j = 0; j < 4; ++j) {
    const int r = (j & 1) * 64 + sr;
    const int kko = (j >> 1) * 32;
    aoff[j] = (size_t)(bm0 + r) * lda + kko + ssub;
    boff[j] = (size_t)(bn0 + r) * ldb + kko + ssub;
  }
  unsigned char* dstA = lds + wid * 1024;           // + j*4096
  unsigned char* dstB = lds + 16384 + wid * 1024;   // + j*4096

  f32x4 acc[4][4] = {};
  const int nkt = K >> 6;
  for (int kt = 0; kt < nkt; ++kt) {
    const int kc = kt << 6;
#pragma unroll
    for (int j = 0; j < 4; ++j) {
      gl_lds16(A + aoff[j] + kc, dstA + j * 4096);
      gl_lds16(B + boff[j] + kc, dstB + j * 4096);
    }
    __syncthreads();

#pragma unroll
    for (int kk = 0; kk < 2; ++kk) {
      bf16x8 af[4], bg[4];
#pragma unroll
      for (int mi = 0; mi < 4; ++mi)
        af[mi] = *(const bf16x8*)(lds + kk * 8192 + (wr * 64 + mi * 16 + l15) * 64 + kq * 16);
#pragma unroll
      for (int ni = 0; ni < 4; ++ni)
        bg[ni] = *(const bf16x8*)(lds + 16384 + kk * 8192 + (wc * 64 + ni * 16 + l15) * 64 + kq * 16);
#pragma unroll
      for (int mi = 0; mi < 4; ++mi)
#pragma unroll
        for (int ni = 0; ni < 4; ++ni)
          acc[mi][ni] = __builtin_amdgcn_mfma_f32_16x16x32_bf16(af[mi], bg[ni], acc[mi][ni], 0, 0, 0);
    }
    __syncthreads();
  }

  // epilogue: C/D layout col = lane&15, row = (lane>>4)*4 + reg  [verified m89/m91]
  if constexpr (MODE == 3) {
#pragma unroll
    for (int mi = 0; mi < 4; ++mi)
#pragma unroll
      for (int ni = 0; ni < 4; ++ni)
#pragma unroll
        for (int r = 0; r < 4; ++r) {
          const int row = bm0 + wr * 64 + mi * 16 + kq * 4 + r;
          const int col = bn0 + wc * 64 + ni * 16 + l15;
          const float v = acc[mi][ni][r];
          unsigned short* q = (unsigned short*)Cv;
          if (col < 1024) {
            q[(size_t)row * 1024 + col] = f2bf(v);
          } else if (col < 2048) {
            q[16777216u + (size_t)row * 1024 + (col - 1024)] = f2bf(v);
          } else {
            const int b = row >> 11, s = row & 2047;
            q[33554432u + ((size_t)(b * 1024 + (col - 2048))) * 2048 + s] = f2bf(v);
          }
        }
  } else if constexpr (MODE == 4) {
    __shared__ float redsm[128][2];
    unsigned short* pp = (unsigned short*)Cv + (size_t)blockIdx.z * cstride;
    float rs[4][4];
#pragma unroll
    for (int mi = 0; mi < 4; ++mi)
#pragma unroll
      for (int r = 0; r < 4; ++r) rs[mi][r] = 0.f;
#pragma unroll
    for (int mi = 0; mi < 4; ++mi)
#pragma unroll
      for (int ni = 0; ni < 4; ++ni)
#pragma unroll
        for (int r = 0; r < 4; ++r) {
          const float e = exp2f(acc[mi][ni][r] * 0.045084220027780106f);  // exp(acc/32)
          rs[mi][r] += e;
          const int row = bm0 + wr * 64 + mi * 16 + kq * 4 + r;
          const int col = bn0 + wc * 64 + ni * 16 + l15;
          pp[(size_t)row * ldc + col] = f2bf(e);
        }
#pragma unroll
    for (int mi = 0; mi < 4; ++mi)
#pragma unroll
      for (int r = 0; r < 4; ++r) {
        float s = rs[mi][r];
        s += __shfl_xor(s, 1); s += __shfl_xor(s, 2);
        s += __shfl_xor(s, 4); s += __shfl_xor(s, 8);
        rs[mi][r] = s;
      }
    if (l15 == 0) {
#pragma unroll
      for (int mi = 0; mi < 4; ++mi)
#pragma unroll
        for (int r = 0; r < 4; ++r)
          redsm[wr * 64 + mi * 16 + kq * 4 + r][wc] = rs[mi][r];
    }
    __syncthreads();
    if (tid < 128)
      aux[((size_t)blockIdx.z * 16 + tx) * 2048 + bm0 + tid] =
          redsm[tid][0] + redsm[tid][1];
  } else {  // MODE 5
    float* op = (float*)Cv + (size_t)blockIdx.z * cstride;
#pragma unroll
    for (int mi = 0; mi < 4; ++mi)
#pragma unroll
      for (int r = 0; r < 4; ++r) {
        const int row = bm0 + wr * 64 + mi * 16 + kq * 4 + r;
        const float iv = smInv[wr * 64 + mi * 16 + kq * 4 + r];
#pragma unroll
        for (int ni = 0; ni < 4; ++ni) {
          const int col = bn0 + wc * 64 + ni * 16 + l15;
          op[(size_t)row * ldc + col] = acc[mi][ni][r] * iv;
        }
      }
  }
}

// ---------- launch ----------
extern "C" void kernel_launch(void* const* d_in, const int* in_sizes, int n_in,
                              void* d_out, int out_size, void* d_ws, size_t ws_size,
                              hipStream_t stream) {
  const float* x  = (const float*)d_in[0];
  const float* Wq = (const float*)d_in[1];
  const float* Wk = (const float*)d_in[2];
  const float* Wv = (const float*)d_in[3];
  float* out = (float*)d_out;
  char* ws = (char*)d_ws;

  // workspace layout (bytes)
  unsigned short* xb     = (unsigned short*)ws;                  // 33.5 MB (dead after QKV)
  unsigned short* wt_all = (unsigned short*)(ws + 33554432);     // 6 MB: WqT|WkT|WvT [3072][1024]
  unsigned short* qb     = (unsigned short*)(ws + 39845888);     // 33.5 MB
  unsigned short* kb     = qb + 16777216;                        // 33.5 MB
  unsigned short* vt     = kb + 16777216;                        // 33.5 MB (vT: [b*1024+e][s])
  const size_t off_scores = 140509184ull;                        // end of vt

  // per-batch attention scratch: P' bf16 8 MiB + partials 128 KiB
  const size_t per_b = 8388608ull + 131072ull;
  int G; char *pPc, *partc;
  const size_t avail = ws_size > off_scores ? ws_size - off_scores : 0;
  G = (int)(avail / per_b); if (G > 8) G = 8;
  if (G >= 1) {
    pPc   = ws + off_scores;
    partc = pPc + (size_t)G * 8388608ull;
  } else {
    G = 2;  // fallback: reuse xb region (33.5 MB >= 2 x 8.53 MB); xb dead after QKV
    pPc   = ws;
    partc = ws + 2 * 8388608ull;
  }

  cast_f32_bf16<<<2048, 256, 0, stream>>>(x, xb, 16384 * 1024);
  transpose_cast_w3<<<dim3(64, 64, 3), 256, 0, stream>>>(Wq, Wk, Wv, wt_all);

  // fused QKV projection: M=16384, N=3072, K=1024 -- 128^2 tile
  gemm_bt<3><<<dim3(24, 128), 256, 0, stream>>>(xb, 1024, 0, wt_all, 1024, 0,
                                                1024, qb, 0, 0, nullptr);

  for (int b0 = 0; b0 < 8; b0 += G) {
    const int g = (8 - b0) < G ? (8 - b0) : G;
    const size_t so = (size_t)b0 * 2097152;  // q/k/v/out batch offset (elems)
    // P' = exp(q.k^T/32) bf16 + partial row sums: M=N=2048, K=1024
    gemm_bt<4><<<dim3(16, 16, g), 256, 0, stream>>>(
        qb + so, 1024, 2097152, kb + so, 1024, 2097152, 1024,
        (unsigned short*)pPc, 2048, 4194304, (float*)partc);
    // out = (P'.v) * inv : A=P' [2048][2048] bf16, B^T = vT_b [1024][2048], K=2048
    // (inv computed in-block from the 16 partials; combine kernel folded away)
    gemm_bt<5><<<dim3(8, 16, g), 256, 0, stream>>>(
        (const unsigned short*)pPc, 2048, 4194304,
        vt + so, 2048, 2097152, 2048,
        out + so, 1024, 2097152, (float*)partc);
  }
}

// Round 15
// 339.766 us; speedup vs baseline: 1.1931x; 1.0033x over previous
//
#include <hip/hip_runtime.h>
#include <hip/hip_bf16.h>

typedef __bf16 bf16x8 __attribute__((ext_vector_type(8)));
typedef float  f32x4  __attribute__((ext_vector_type(4)));

// ---------- helpers ----------
static __device__ __forceinline__ unsigned short f2bf(float f) {
  unsigned int u = __float_as_uint(f);
  u += 0x7FFFu + ((u >> 16) & 1u);   // round-to-nearest-even
  return (unsigned short)(u >> 16);
}

static __device__ __forceinline__ void gl_lds16(const void* g, void* l) {
  __builtin_amdgcn_global_load_lds(
      (const __attribute__((address_space(1))) void*)g,
      (__attribute__((address_space(3))) void*)l,
      16, 0, 0);
}

// ---------- cast x: f32 -> bf16 ----------
__global__ __launch_bounds__(256) void cast_f32_bf16(
    const float* __restrict__ in, unsigned short* __restrict__ out, int n) {
  int i = (blockIdx.x * 256 + threadIdx.x) * 4;
  const int stride = gridDim.x * 256 * 4;
  for (; i < n; i += stride) {
    float4 f = *(const float4*)(in + i);
    ushort4 o;
    o.x = f2bf(f.x); o.y = f2bf(f.y); o.z = f2bf(f.z); o.w = f2bf(f.w);
    *(ushort4*)(out + i) = o;
  }
}

// ---------- transpose-cast Wq|Wk|Wv in one launch (z picks the matrix) ----------
__global__ __launch_bounds__(256) void transpose_cast_w3(
    const float* __restrict__ w0, const float* __restrict__ w1,
    const float* __restrict__ w2, unsigned short* __restrict__ wt) {
  __shared__ float tile[16][17];
  const float* w = blockIdx.z == 0 ? w0 : (blockIdx.z == 1 ? w1 : w2);
  unsigned short* o = wt + (size_t)blockIdx.z * 1048576;
  const int tx = threadIdx.x & 15, ty = threadIdx.x >> 4;
  const int bx = blockIdx.x * 16, by = blockIdx.y * 16;
  tile[ty][tx] = w[(size_t)(by + ty) * 1024 + bx + tx];
  __syncthreads();
  o[(size_t)(bx + ty) * 1024 + by + tx] = f2bf(tile[tx][ty]);
}

// ---------- 128x128-tile bf16 GEMM, BK=64 single buffer, 8 WAVES/BLOCK ----------
// Same LDS layout & schedule as the r7/r14 champion; only the wave count
// changes. Diagnosis (r14): 256-thread blocks + 32 KB LDS cap residency at
// 4 blocks = 16 waves/CU (39% occ) -> per-SIMD only ~3 independent waves to
// hide the per-iter barrier drain; MfmaUtil stuck at 27%. 512-thread blocks
// give 8 waves/block x 4 LDS-resident blocks = up to 32 waves/CU with the
// SAME footprint. __launch_bounds__(512,7) caps VGPR ~73 (acc[4][2]=32 +
// frags 24 + addr) so VGPR doesn't undo the residency gain.
// Wave grid 2M x 4N; per-wave output 64x32; per iter per wave: 12 ds_read +
// 16 MFMA. Staging: thread chunk c=tid covers row tid>>2, 16B slot tid&3 of
// [kk=0]; +32 elems = same row [kk=1] -- 64 B-contiguous per 4 lanes (full
// cache lines), linear LDS dest (wave base wid*1024 + lane*16, j=1 at +8192).
// MODE 3: fused-QKV split write (Cv = qb base; kb = +16Mi elems, vt = +32Mi)
// MODE 4: scores + fused exp + per-block partial row-sums
// MODE 5: PV; inv computed IN-BLOCK from the 16 partials
template <int MODE>
__global__ __launch_bounds__(512, 7) void gemm_bt(
    const unsigned short* __restrict__ A, int lda, size_t astride,
    const unsigned short* __restrict__ B, int ldb, size_t bstride,
    int K, void* __restrict__ Cv, int ldc, size_t cstride,
    float* __restrict__ aux) {
  __shared__ __align__(16) unsigned char lds[32768];  // A 16K [kk][row][64B] | B 16K
  __shared__ float smInv[128];
  const unsigned d2 = blockIdx.x + gridDim.x * blockIdx.y;
  const unsigned ty = d2 % gridDim.y;
  const unsigned tx = d2 / gridDim.y;
  const int bn0 = tx * 128;
  const int bm0 = ty * 128;
  A += (size_t)blockIdx.z * astride;
  B += (size_t)blockIdx.z * bstride;

  const int tid = threadIdx.x;
  const int wid = tid >> 6, lane = tid & 63;
  const int wr = wid >> 2, wc = wid & 3;     // wave grid 2(M) x 4(N)
  const int l15 = lane & 15, kq = lane >> 4;

  if constexpr (MODE == 5) {  // inv[row] for this block's 128 rows
    if (tid < 128) {
      const float* p = aux + (size_t)blockIdx.z * 32768 + bm0 + tid;
      float s = 0.f;
#pragma unroll
      for (int j = 0; j < 16; ++j) s += p[j * 2048];
      smInv[tid] = 1.0f / s;   // visible after iter-0 __syncthreads
    }
  }

  // staging: row = tid>>2, 16B slot = tid&3; j=0 -> kk=0, j=1 -> kk=1 (+32 elems)
  const int sr = tid >> 2;
  const int ssub = (tid & 3) * 8;
  const size_t aoff = (size_t)(bm0 + sr) * lda + ssub;
  const size_t boff = (size_t)(bn0 + sr) * ldb + ssub;
  unsigned char* dstA = lds + wid * 1024;            // j=1 at +8192
  unsigned char* dstB = lds + 16384 + wid * 1024;    // j=1 at +8192

  f32x4 acc[4][2] = {};
  const int nkt = K >> 6;
  for (int kt = 0; kt < nkt; ++kt) {
    const int kc = kt << 6;
    gl_lds16(A + aoff + kc,      dstA);
    gl_lds16(A + aoff + kc + 32, dstA + 8192);
    gl_lds16(B + boff + kc,      dstB);
    gl_lds16(B + boff + kc + 32, dstB + 8192);
    __syncthreads();

#pragma unroll
    for (int kk = 0; kk < 2; ++kk) {
      bf16x8 af[4], bg[2];
#pragma unroll
      for (int mi = 0; mi < 4; ++mi)
        af[mi] = *(const bf16x8*)(lds + kk * 8192 + (wr * 64 + mi * 16 + l15) * 64 + kq * 16);
#pragma unroll
      for (int ni = 0; ni < 2; ++ni)
        bg[ni] = *(const bf16x8*)(lds + 16384 + kk * 8192 + (wc * 32 + ni * 16 + l15) * 64 + kq * 16);
#pragma unroll
      for (int mi = 0; mi < 4; ++mi)
#pragma unroll
        for (int ni = 0; ni < 2; ++ni)
          acc[mi][ni] = __builtin_amdgcn_mfma_f32_16x16x32_bf16(af[mi], bg[ni], acc[mi][ni], 0, 0, 0);
    }
    __syncthreads();
  }

  // epilogue: C/D layout col = lane&15, row = (lane>>4)*4 + reg  [verified m89/m91]
  if constexpr (MODE == 3) {
#pragma unroll
    for (int mi = 0; mi < 4; ++mi)
#pragma unroll
      for (int ni = 0; ni < 2; ++ni)
#pragma unroll
        for (int r = 0; r < 4; ++r) {
          const int row = bm0 + wr * 64 + mi * 16 + kq * 4 + r;
          const int col = bn0 + wc * 32 + ni * 16 + l15;
          const float v = acc[mi][ni][r];
          unsigned short* q = (unsigned short*)Cv;
          if (col < 1024) {
            q[(size_t)row * 1024 + col] = f2bf(v);
          } else if (col < 2048) {
            q[16777216u + (size_t)row * 1024 + (col - 1024)] = f2bf(v);
          } else {
            const int b = row >> 11, s = row & 2047;
            q[33554432u + ((size_t)(b * 1024 + (col - 2048))) * 2048 + s] = f2bf(v);
          }
        }
  } else if constexpr (MODE == 4) {
    __shared__ float redsm[128][4];
    unsigned short* pp = (unsigned short*)Cv + (size_t)blockIdx.z * cstride;
    float rs[4][4];
#pragma unroll
    for (int mi = 0; mi < 4; ++mi)
#pragma unroll
      for (int r = 0; r < 4; ++r) rs[mi][r] = 0.f;
#pragma unroll
    for (int mi = 0; mi < 4; ++mi)
#pragma unroll
      for (int ni = 0; ni < 2; ++ni)
#pragma unroll
        for (int r = 0; r < 4; ++r) {
          const float e = exp2f(acc[mi][ni][r] * 0.045084220027780106f);  // exp(acc/32)
          rs[mi][r] += e;
          const int row = bm0 + wr * 64 + mi * 16 + kq * 4 + r;
          const int col = bn0 + wc * 32 + ni * 16 + l15;
          pp[(size_t)row * ldc + col] = f2bf(e);
        }
    // reduce each row's 32-col wave partial over the 16 l15 lanes
#pragma unroll
    for (int mi = 0; mi < 4; ++mi)
#pragma unroll
      for (int r = 0; r < 4; ++r) {
        float s = rs[mi][r];
        s += __shfl_xor(s, 1); s += __shfl_xor(s, 2);
        s += __shfl_xor(s, 4); s += __shfl_xor(s, 8);
        rs[mi][r] = s;
      }
    if (l15 == 0) {
#pragma unroll
      for (int mi = 0; mi < 4; ++mi)
#pragma unroll
        for (int r = 0; r < 4; ++r)
          redsm[wr * 64 + mi * 16 + kq * 4 + r][wc] = rs[mi][r];
    }
    __syncthreads();
    if (tid < 128)
      aux[((size_t)blockIdx.z * 16 + tx) * 2048 + bm0 + tid] =
          redsm[tid][0] + redsm[tid][1] + redsm[tid][2] + redsm[tid][3];
  } else {  // MODE 5
    float* op = (float*)Cv + (size_t)blockIdx.z * cstride;
#pragma unroll
    for (int mi = 0; mi < 4; ++mi)
#pragma unroll
      for (int r = 0; r < 4; ++r) {
        const int row = bm0 + wr * 64 + mi * 16 + kq * 4 + r;
        const float iv = smInv[wr * 64 + mi * 16 + kq * 4 + r];
#pragma unroll
        for (int ni = 0; ni < 2; ++ni) {
          const int col = bn0 + wc * 32 + ni * 16 + l15;
          op[(size_t)row * ldc + col] = acc[mi][ni][r] * iv;
        }
      }
  }
}

// ---------- launch ----------
extern "C" void kernel_launch(void* const* d_in, const int* in_sizes, int n_in,
                              void* d_out, int out_size, void* d_ws, size_t ws_size,
                              hipStream_t stream) {
  const float* x  = (const float*)d_in[0];
  const float* Wq = (const float*)d_in[1];
  const float* Wk = (const float*)d_in[2];
  const float* Wv = (const float*)d_in[3];
  float* out = (float*)d_out;
  char* ws = (char*)d_ws;

  // workspace layout (bytes)
  unsigned short* xb     = (unsigned short*)ws;                  // 33.5 MB (dead after QKV)
  unsigned short* wt_all = (unsigned short*)(ws + 33554432);     // 6 MB: WqT|WkT|WvT [3072][1024]
  unsigned short* qb     = (unsigned short*)(ws + 39845888);     // 33.5 MB
  unsigned short* kb     = qb + 16777216;                        // 33.5 MB
  unsigned short* vt     = kb + 16777216;                        // 33.5 MB (vT: [b*1024+e][s])
  const size_t off_scores = 140509184ull;                        // end of vt

  // per-batch attention scratch: P' bf16 8 MiB + partials 128 KiB
  const size_t per_b = 8388608ull + 131072ull;
  int G; char *pPc, *partc;
  const size_t avail = ws_size > off_scores ? ws_size - off_scores : 0;
  G = (int)(avail / per_b); if (G > 8) G = 8;
  if (G >= 1) {
    pPc   = ws + off_scores;
    partc = pPc + (size_t)G * 8388608ull;
  } else {
    G = 2;  // fallback: reuse xb region (33.5 MB >= 2 x 8.53 MB); xb dead after QKV
    pPc   = ws;
    partc = ws + 2 * 8388608ull;
  }

  cast_f32_bf16<<<2048, 256, 0, stream>>>(x, xb, 16384 * 1024);
  transpose_cast_w3<<<dim3(64, 64, 3), 256, 0, stream>>>(Wq, Wk, Wv, wt_all);

  // fused QKV projection: M=16384, N=3072, K=1024 -- 128^2 tile, 512-thread blocks
  gemm_bt<3><<<dim3(24, 128), 512, 0, stream>>>(xb, 1024, 0, wt_all, 1024, 0,
                                                1024, qb, 0, 0, nullptr);

  for (int b0 = 0; b0 < 8; b0 += G) {
    const int g = (8 - b0) < G ? (8 - b0) : G;
    const size_t so = (size_t)b0 * 2097152;  // q/k/v/out batch offset (elems)
    // P' = exp(q.k^T/32) bf16 + partial row sums: M=N=2048, K=1024
    gemm_bt<4><<<dim3(16, 16, g), 512, 0, stream>>>(
        qb + so, 1024, 2097152, kb + so, 1024, 2097152, 1024,
        (unsigned short*)pPc, 2048, 4194304, (float*)partc);
    // out = (P'.v) * inv : A=P' [2048][2048] bf16, B^T = vT_b [1024][2048], K=2048
    // (inv computed in-block from the 16 partials; combine kernel folded away)
    gemm_bt<5><<<dim3(8, 16, g), 512, 0, stream>>>(
        (const unsigned short*)pPc, 2048, 4194304,
        vt + so, 2048, 2097152, 2048,
        out + so, 1024, 2097152, (float*)partc);
  }
}